// Round 1
// baseline (110.715 us; speedup 1.0000x reference)
//
#include <hip/hip_runtime.h>

#define THRESH 1.0f
#define DECAY  0.5f

__global__ __launch_bounds__(256) void lif_kernel(const float* __restrict__ X,
                                                  float* __restrict__ S,
                                                  long long n_neurons) {
    long long idx    = (long long)blockIdx.x * blockDim.x + threadIdx.x;
    long long stride = (long long)gridDim.x * blockDim.x;
    for (long long i = idx; i < n_neurons; i += stride) {
        const float4* __restrict__ xp = reinterpret_cast<const float4*>(X + i * 8);
        float4 x0 = xp[0];
        float4 x1 = xp[1];
        float xv[8] = {x0.x, x0.y, x0.z, x0.w, x1.x, x1.y, x1.z, x1.w};
        float sv[8];
        float mem = 0.0f;
#pragma unroll
        for (int t = 0; t < 8; ++t) {
            mem = mem * DECAY + xv[t];
            bool fired = (mem >= THRESH);
            sv[t] = fired ? 1.0f : 0.0f;
            mem   = fired ? 0.0f : mem;   // reset fired neurons -> v_cndmask
        }
        float4* __restrict__ op = reinterpret_cast<float4*>(S + i * 8);
        op[0] = make_float4(sv[0], sv[1], sv[2], sv[3]);
        op[1] = make_float4(sv[4], sv[5], sv[6], sv[7]);
    }
}

extern "C" void kernel_launch(void* const* d_in, const int* in_sizes, int n_in,
                              void* d_out, int out_size, void* d_ws, size_t ws_size,
                              hipStream_t stream) {
    const float* X = (const float*)d_in[0];
    float* S = (float*)d_out;
    long long n_elems   = (long long)in_sizes[0];
    long long n_neurons = n_elems / 8;  // T = 8, last axis

    const int block = 256;
    long long want_blocks = (n_neurons + block - 1) / block;
    int grid = (int)(want_blocks < 2048 ? want_blocks : 2048);  // 256 CU x 8 blocks, grid-stride

    lif_kernel<<<grid, block, 0, stream>>>(X, S, n_neurons);
}

// Round 2
// 110.682 us; speedup vs baseline: 1.0003x; 1.0003x over previous
//
#include <hip/hip_runtime.h>

#define THRESH 1.0f
#define DECAY  0.5f

typedef float f32x4 __attribute__((ext_vector_type(4)));

constexpr int BLOCK = 256;
constexpr int NEUR_PER_THREAD = 2;
constexpr int TILE_NEURONS = BLOCK * NEUR_PER_THREAD;   // 512 neurons / tile
constexpr int PAD = 12;                                 // floats per neuron in LDS (48 B, 16B-aligned)

__global__ __launch_bounds__(BLOCK) void lif_kernel(const float* __restrict__ X,
                                                    float* __restrict__ S,
                                                    long long n_neurons) {
    __shared__ float lds[TILE_NEURONS * PAD];           // 24 KiB
    const int tid = threadIdx.x;
    const long long total_f4 = n_neurons * 2;           // 2 float4 per neuron
    const long long n_tiles = (n_neurons + TILE_NEURONS - 1) / TILE_NEURONS;

    const f32x4* __restrict__ Xv = reinterpret_cast<const f32x4*>(X);
    f32x4* __restrict__ Sv = reinterpret_cast<f32x4*>(S);

    for (long long tile = blockIdx.x; tile < n_tiles; tile += gridDim.x) {
        const long long base_f4 = tile * (long long)TILE_NEURONS * 2;

        // Phase 1: contiguous global -> padded LDS
#pragma unroll
        for (int k = 0; k < 4; ++k) {
            int g = tid + k * BLOCK;                    // 0..1023 float4s in tile
            long long gi = base_f4 + g;
            if (gi < total_f4) {
                f32x4 v = __builtin_nontemporal_load(&Xv[gi]);
                int neuron = g >> 1;
                int e4 = (g & 1) * 4;
                *reinterpret_cast<f32x4*>(&lds[neuron * PAD + e4]) = v;
            }
        }
        __syncthreads();

        // Phase 2: per-neuron recurrence in registers, spikes written back in place
#pragma unroll
        for (int r = 0; r < NEUR_PER_THREAD; ++r) {
            int ln = tid + r * BLOCK;                   // local neuron 0..511
            long long gn = tile * (long long)TILE_NEURONS + ln;
            if (gn < n_neurons) {
                f32x4 a = *reinterpret_cast<const f32x4*>(&lds[ln * PAD + 0]);
                f32x4 b = *reinterpret_cast<const f32x4*>(&lds[ln * PAD + 4]);
                float xv[8] = {a[0], a[1], a[2], a[3], b[0], b[1], b[2], b[3]};
                float sv[8];
                float mem = 0.0f;
#pragma unroll
                for (int t = 0; t < 8; ++t) {
                    mem = mem * DECAY + xv[t];
                    bool fired = (mem >= THRESH);
                    sv[t] = fired ? 1.0f : 0.0f;
                    mem   = fired ? 0.0f : mem;
                }
                f32x4 s0 = {sv[0], sv[1], sv[2], sv[3]};
                f32x4 s1 = {sv[4], sv[5], sv[6], sv[7]};
                *reinterpret_cast<f32x4*>(&lds[ln * PAD + 0]) = s0;
                *reinterpret_cast<f32x4*>(&lds[ln * PAD + 4]) = s1;
            }
        }
        __syncthreads();

        // Phase 3: padded LDS -> contiguous global (nontemporal streaming store)
#pragma unroll
        for (int k = 0; k < 4; ++k) {
            int g = tid + k * BLOCK;
            long long gi = base_f4 + g;
            if (gi < total_f4) {
                int neuron = g >> 1;
                int e4 = (g & 1) * 4;
                f32x4 s = *reinterpret_cast<const f32x4*>(&lds[neuron * PAD + e4]);
                __builtin_nontemporal_store(s, &Sv[gi]);
            }
        }
        __syncthreads();   // protect LDS reuse across grid-stride iterations
    }
}

extern "C" void kernel_launch(void* const* d_in, const int* in_sizes, int n_in,
                              void* d_out, int out_size, void* d_ws, size_t ws_size,
                              hipStream_t stream) {
    const float* X = (const float*)d_in[0];
    float* S = (float*)d_out;
    long long n_elems   = (long long)in_sizes[0];
    long long n_neurons = n_elems / 8;   // T = 8, last (contiguous) axis

    const int block = BLOCK;
    long long n_tiles = (n_neurons + TILE_NEURONS - 1) / TILE_NEURONS;
    int grid = (int)(n_tiles < 2048 ? n_tiles : 2048);

    lif_kernel<<<grid, block, 0, stream>>>(X, S, n_neurons);
}